// Round 12
// baseline (237.509 us; speedup 1.0000x reference)
//
#include <hip/hip_runtime.h>

#define N_USER 100000
#define N_ITEM 100000
#define NEDGE  500000
#define DEGCAP 32
#define NPART  12504   // nodes per XCD partition (8*12504 >= 100032)

// setup_k grid roles (by raw blockIdx, no permutation):
//   r % 7 == 0 && r/7 < 976  -> XCD-partitioned CSR fill (976 blocks)
//   otherwise                -> emb conversion (12500) then weight prep (384)
#define B_FILLN 976
#define B_TOT   13860  // 976 + 12500 + 384

typedef __attribute__((ext_vector_type(8))) short short8;
typedef __attribute__((ext_vector_type(4))) float f32x4;

__device__ __forceinline__ unsigned short f2bf(float f) {
  union { float f; unsigned int u; } x{f};
  unsigned int r = x.u + 0x7fffu + ((x.u >> 16) & 1u);  // RTN-even
  return (unsigned short)(r >> 16);
}
__device__ __forceinline__ float bf2f(unsigned short u) {
  union { unsigned int u; float f; } x{(unsigned int)u << 16};
  return x.f;
}

// ---------------------------------------------------------------------------
// setup_k:
//  FILL (XCD-partitioned): block r=7*fi assumes XCD = r&7 (round-robin
//    dispatch heuristic; perf-only). Partition p = r&7 owns nodes
//    [p*NPART,(p+1)*NPART). rank = fi>>3 scans edge chunk [rank*8197, +8197)
//    over the concatenated 1M edges (both graphs), processing only edges
//    whose dst is in p. All cur/csr lines for p are touched by ONE XCD ->
//    no cross-XCD L2 line bouncing (R11: 2.3x write amplification).
//  CONV: emb fp32 -> bf16.   WT: transposed bf16 weight prep WT[N][256].
// ---------------------------------------------------------------------------
__global__ __launch_bounds__(256) void setup_k(
    const int* __restrict__ src_ui, const int* __restrict__ dst_ui,
    int* __restrict__ cur_i, int* __restrict__ csr_ui,
    const int* __restrict__ src_iu, const int* __restrict__ dst_iu,
    int* __restrict__ cur_u, int* __restrict__ csr_iu,
    const float* __restrict__ emb_u, const float* __restrict__ emb_i,
    unsigned short* __restrict__ ebu, unsigned short* __restrict__ ebi,
    const float* __restrict__ W10, const float* __restrict__ W1ui,
    const float* __restrict__ W1iu, const float* __restrict__ W20,
    const float* __restrict__ W2ui, const float* __restrict__ W2iu,
    unsigned short* __restrict__ WT1i, unsigned short* __restrict__ WT1u,
    unsigned short* __restrict__ WT2i, unsigned short* __restrict__ WT2u) {
  int r = blockIdx.x, tid = threadIdx.x;
  bool isfill = (r % 7 == 0) && (r / 7 < B_FILLN);
  if (isfill) {
    int fi = r / 7;
    int p = r & 7;            // assumed XCD (r = 7*fi cycles all residues)
    int rank = fi >> 3;       // 0..121 within partition
    int lo = p * NPART, hi = lo + NPART;
    int e0 = rank * 8197;
    int e1 = e0 + 8197; if (e1 > 2 * NEDGE) e1 = 2 * NEDGE;
    for (int e = e0 + tid; e < e1; e += 256) {
      const int *src, *dst; int *cur, *csr; int ee = e;
      if (ee < NEDGE) { src = src_ui; dst = dst_ui; cur = cur_i; csr = csr_ui; }
      else { ee -= NEDGE; src = src_iu; dst = dst_iu; cur = cur_u; csr = csr_iu; }
      int d = dst[ee];
      if (d >= lo && d < hi) {
        int pos = atomicAdd(&cur[d], 1);
        if (pos < DEGCAP) csr[d * DEGCAP + pos] = src[ee];
      }
    }
  } else {
    int nf = (r + 6) / 7; if (nf > B_FILLN) nf = B_FILLN;
    int sr = r - nf;  // [0, 12884)
    if (sr < 12500) {
      int blk = sr;
      const float* src; unsigned short* dstp;
      if (blk < 6250) { src = emb_u; dstp = ebu; }
      else { blk -= 6250; src = emb_i; dstp = ebi; }
      size_t g = (size_t)blk * 2048 + (size_t)tid * 8;
      float4 x = *(const float4*)(src + g);
      float4 y = *(const float4*)(src + g + 4);
      short8 v{(short)f2bf(x.x), (short)f2bf(x.y), (short)f2bf(x.z), (short)f2bf(x.w),
               (short)f2bf(y.x), (short)f2bf(y.y), (short)f2bf(y.z), (short)f2bf(y.w)};
      *(short8*)(dstp + g) = v;
    } else {
      int t = (sr - 12500) * 256 + tid;  // 0..98303
      if (t < 32768) {
        int n = t >> 8, k = t & 255;
        float v = (k < 128) ? W10[k * 128 + n] : W1ui[(k - 128) * 128 + n];
        WT1i[t] = f2bf(v);
      } else if (t < 65536) {
        int q = t - 32768; int n = q >> 8, k = q & 255;
        float v = (k < 128) ? W10[k * 128 + n] : W1iu[(k - 128) * 128 + n];
        WT1u[q] = f2bf(v);
      } else if (t < 81920) {
        int q = t - 65536; int n = q >> 8, k = q & 255;
        float v = (k < 128) ? W20[k * 64 + n] : W2ui[(k - 128) * 64 + n];
        WT2i[q] = f2bf(v);
      } else {
        int q = t - 81920; int n = q >> 8, k = q & 255;
        float v = (k < 128) ? W20[k * 64 + n] : W2iu[(k - 128) * 64 + n];
        WT2u[q] = f2bf(v);
      }
    }
  }
}

// ---------------------------------------------------------------------------
// Gather-mean aggregation (bf16, 128-dim), both directions per dispatch.
// Per node (16 lanes): one coalesced 128B csr-row read (int2/lane) into LDS,
// then the x4-unrolled gather pipeline reads indices from LDS (broadcast).
// No LDS staging of features, high occupancy (R5 lesson).
// ---------------------------------------------------------------------------
__global__ __launch_bounds__(256) void aggc_k(
    const unsigned short* __restrict__ featA, const int* __restrict__ curA,
    const int* __restrict__ csrA, unsigned short* __restrict__ outA,
    const unsigned short* __restrict__ featB, const int* __restrict__ curB,
    const int* __restrict__ csrB, unsigned short* __restrict__ outB,
    int nbA) {
  __shared__ int sidx[16][32];
  int b = blockIdx.x;
  const unsigned short* feat; const int* cur; const int* csr; unsigned short* out;
  if (b < nbA) { feat = featA; cur = curA; csr = csrA; out = outA; }
  else { b -= nbA; feat = featB; cur = curB; csr = csrB; out = outB; }
  int grp = threadIdx.x >> 4;
  int ln  = threadIdx.x & 15;
  int node = b * 16 + grp;
  int deg = min(cur[node], DEGCAP);

  int2 sl = *(const int2*)(csr + (size_t)node * DEGCAP + ln * 2);
  sidx[grp][ln * 2] = sl.x;
  sidx[grp][ln * 2 + 1] = sl.y;
  __syncthreads();

  const int* lidx = sidx[grp];
  float a[8] = {0, 0, 0, 0, 0, 0, 0, 0};
  int j = 0;
  if (j + 4 <= deg) {
    int i0 = lidx[0], i1 = lidx[1], i2 = lidx[2], i3 = lidx[3];
    for (;;) {
      bool more = (j + 8 <= deg);
      int n0, n1, n2, n3;
      if (more) { n0 = lidx[j + 4]; n1 = lidx[j + 5]; n2 = lidx[j + 6]; n3 = lidx[j + 7]; }
      short8 v0 = *(const short8*)(feat + (size_t)i0 * 128 + ln * 8);
      short8 v1 = *(const short8*)(feat + (size_t)i1 * 128 + ln * 8);
      short8 v2 = *(const short8*)(feat + (size_t)i2 * 128 + ln * 8);
      short8 v3 = *(const short8*)(feat + (size_t)i3 * 128 + ln * 8);
#pragma unroll
      for (int d = 0; d < 8; ++d)
        a[d] += (bf2f((unsigned short)v0[d]) + bf2f((unsigned short)v1[d])) +
                (bf2f((unsigned short)v2[d]) + bf2f((unsigned short)v3[d]));
      j += 4;
      if (!more) break;
      i0 = n0; i1 = n1; i2 = n2; i3 = n3;
    }
  }
  if (j + 2 <= deg) {
    int i0 = lidx[j], i1 = lidx[j + 1];
    short8 v0 = *(const short8*)(feat + (size_t)i0 * 128 + ln * 8);
    short8 v1 = *(const short8*)(feat + (size_t)i1 * 128 + ln * 8);
#pragma unroll
    for (int d = 0; d < 8; ++d)
      a[d] += bf2f((unsigned short)v0[d]) + bf2f((unsigned short)v1[d]);
    j += 2;
  }
  if (j < deg) {
    short8 v = *(const short8*)(feat + (size_t)lidx[j] * 128 + ln * 8);
#pragma unroll
    for (int d = 0; d < 8; ++d) a[d] += bf2f((unsigned short)v[d]);
  }
  float sc = deg ? 1.f / (float)deg : 0.f;
  short8 pk;
#pragma unroll
  for (int d = 0; d < 8; ++d) pk[d] = (short)f2bf(a[d] * sc);
  *(short8*)(out + (size_t)node * 128 + ln * 8) = pk;
}

// ---------------------------------------------------------------------------
// Fused double-GEMM (bf16 MFMA, fp32 accum), both ntypes per dispatch:
//   out = A1@W[0:128] + A2@W[128:256] + b0 + (deg>0)*be  [, lrelu]
// LDS XOR-swizzled. In-place out==A1 (and gemm2's agg alias in d_out) safe:
// block reads only its own rows, all stage-reads precede epilogue writes.
// ---------------------------------------------------------------------------
template <int N, bool LRELU, bool OUTBF16>
__global__ __launch_bounds__(256) void gemm2_k(
    const unsigned short* __restrict__ A1a, const unsigned short* __restrict__ A2a,
    const unsigned short* __restrict__ WTa, const float* __restrict__ b0a,
    const float* __restrict__ bea, const int* __restrict__ cura,
    void* __restrict__ outa,
    const unsigned short* __restrict__ A1b, const unsigned short* __restrict__ A2b,
    const unsigned short* __restrict__ WTb, const float* __restrict__ b0b,
    const float* __restrict__ beb, const int* __restrict__ curb,
    void* __restrict__ outb, int M, int nbA) {
  constexpr int BM = 64;
  constexpr int CPW = N / 4;
  constexpr int NCF = CPW / 16;
  __shared__ short As[BM * 128];
  __shared__ short Ws[N * 128];
  __shared__ float degmask[BM];

  int blk = blockIdx.x;
  const unsigned short* A1; const unsigned short* A2; const unsigned short* WT;
  const float* b0; const float* be; const int* cur; void* outv;
  if (blk < nbA) { A1 = A1a; A2 = A2a; WT = WTa; b0 = b0a; be = bea; cur = cura; outv = outa; }
  else { blk -= nbA; A1 = A1b; A2 = A2b; WT = WTb; b0 = b0b; be = beb; cur = curb; outv = outb; }

  const int tid = threadIdx.x;
  const int lane = tid & 63;
  const int wave = tid >> 6;
  const int row0 = blk * BM;
  const int colbase = wave * CPW;

  if (tid < BM) {
    int r = row0 + tid;
    degmask[tid] = (r < M && cur[r] > 0) ? 1.f : 0.f;
  }

  f32x4 acc[4][NCF] = {};

#pragma unroll
  for (int kh = 0; kh < 2; ++kh) {
    __syncthreads();
    const unsigned short* base = (kh == 0) ? A1 : A2;
#pragma unroll
    for (int it = 0; it < 4; ++it) {
      int chunk = tid + it * 256;
      int row = chunk >> 4, c16 = chunk & 15;
      int gr = row0 + row; if (gr > M - 1) gr = M - 1;
      short8 v = *(const short8*)(base + (size_t)gr * 128 + c16 * 8);
      int byteoff = row * 256 + ((c16 * 16) ^ ((row & 7) << 4));
      *(short8*)((char*)As + byteoff) = v;
    }
#pragma unroll
    for (int it = 0; it < (N * 16) / 256; ++it) {
      int chunk = tid + it * 256;
      int n = chunk >> 4, c16 = chunk & 15;
      short8 v = *(const short8*)(WT + (size_t)n * 256 + kh * 128 + c16 * 8);
      int byteoff = n * 256 + ((c16 * 16) ^ ((n & 7) << 4));
      *(short8*)((char*)Ws + byteoff) = v;
    }
    __syncthreads();

#pragma unroll
    for (int ks = 0; ks < 4; ++ks) {
      short8 af[4];
#pragma unroll
      for (int rf = 0; rf < 4; ++rf) {
        int row = rf * 16 + (lane & 15);
        int c16 = ks * 4 + (lane >> 4);
        int byteoff = row * 256 + ((c16 * 16) ^ ((row & 7) << 4));
        af[rf] = *(const short8*)((const char*)As + byteoff);
      }
      short8 wf[NCF];
#pragma unroll
      for (int cf = 0; cf < NCF; ++cf) {
        int n = colbase + cf * 16 + (lane & 15);
        int c16 = ks * 4 + (lane >> 4);
        int byteoff = n * 256 + ((c16 * 16) ^ ((n & 7) << 4));
        wf[cf] = *(const short8*)((const char*)Ws + byteoff);
      }
#pragma unroll
      for (int rf = 0; rf < 4; ++rf)
#pragma unroll
        for (int cf = 0; cf < NCF; ++cf)
          acc[rf][cf] = __builtin_amdgcn_mfma_f32_16x16x32_bf16(
              af[rf], wf[cf], acc[rf][cf], 0, 0, 0);
    }
  }

  // C/D layout: col=lane&15, row=(lane>>4)*4+j  [m89 verified]
#pragma unroll
  for (int cf = 0; cf < NCF; ++cf) {
    int c = colbase + cf * 16 + (lane & 15);
    float bb0 = b0[c], bbe = be[c];
#pragma unroll
    for (int rf = 0; rf < 4; ++rf) {
#pragma unroll
      for (int j = 0; j < 4; ++j) {
        int lr = rf * 16 + (lane >> 4) * 4 + j;
        int r = row0 + lr;
        if (r < M) {
          float v = acc[rf][cf][j] + bb0 + degmask[lr] * bbe;
          if (LRELU) v = (v >= 0.f) ? v : 0.01f * v;
          if (OUTBF16)
            ((unsigned short*)outv)[(size_t)r * N + c] = f2bf(v);
          else
            ((float*)outv)[(size_t)r * N + c] = v;
        }
      }
    }
  }
}

extern "C" void kernel_launch(void* const* d_in, const int* in_sizes, int n_in,
                              void* d_out, int out_size, void* d_ws,
                              size_t ws_size, hipStream_t stream) {
  const float* emb_u = (const float*)d_in[0];
  const float* emb_i = (const float*)d_in[1];
  const float* W1_0  = (const float*)d_in[2];
  const float* b1_0  = (const float*)d_in[3];
  const float* W1_ui = (const float*)d_in[4];
  const float* b1_ui = (const float*)d_in[5];
  const float* W1_iu = (const float*)d_in[6];
  const float* b1_iu = (const float*)d_in[7];
  const float* W2_0  = (const float*)d_in[8];
  const float* b2_0  = (const float*)d_in[9];
  const float* W2_ui = (const float*)d_in[10];
  const float* b2_ui = (const float*)d_in[11];
  const float* W2_iu = (const float*)d_in[12];
  const float* b2_iu = (const float*)d_in[13];
  const int* src_ui = (const int*)d_in[14];
  const int* dst_ui = (const int*)d_in[15];
  const int* src_iu = (const int*)d_in[16];
  const int* dst_iu = (const int*)d_in[17];
  float* out = (float*)d_out;

  // ---- workspace layout (~78 MB) ----
  char* p = (char*)d_ws;
  unsigned short* WT1i = (unsigned short*)p; p += 65536;
  unsigned short* WT1u = (unsigned short*)p; p += 65536;
  unsigned short* WT2i = (unsigned short*)p; p += 32768;
  unsigned short* WT2u = (unsigned short*)p; p += 32768;
  int* cur_i = (int*)p; p += 400128;
  int* cur_u = (int*)p; p += 400128;
  int* csr_ui = (int*)p; p += (size_t)100032 * DEGCAP * 4;  // 12.8 MB
  int* csr_iu = (int*)p; p += (size_t)100032 * DEGCAP * 4;
  const size_t FB = (size_t)N_USER * 128 * 2;        // 25.6 MB
  unsigned short* ebu  = (unsigned short*)p; p += FB;  // -> hu (in place)
  unsigned short* ebi  = (unsigned short*)p; p += FB;  // -> hi (in place)
  unsigned short* hu = ebu;
  unsigned short* hi = ebi;
  // agg buffers alias d_out (dead until gemm2, which reads each agg row
  // then overwrites the identical bytes; read-before-write within block,
  // disjoint rows across blocks):
  unsigned short* aggB = (unsigned short*)out;                          // user
  unsigned short* aggA = (unsigned short*)(out + (size_t)N_USER * 64);  // item

  const int GG = (N_USER + 63) / 64;  // 1563

  hipMemsetAsync(cur_i, 0, 2 * 400128, stream);
  setup_k<<<B_TOT, 256, 0, stream>>>(src_ui, dst_ui, cur_i, csr_ui,
                                     src_iu, dst_iu, cur_u, csr_iu,
                                     emb_u, emb_i, ebu, ebi,
                                     W1_0, W1_ui, W1_iu, W2_0, W2_ui, W2_iu,
                                     WT1i, WT1u, WT2i, WT2u);

  // ---- layer 1: gather-mean (both dirs), fused double-GEMM + lrelu ----
  aggc_k<<<2 * 6250, 256, 0, stream>>>(
      ebu, cur_i, csr_ui, aggA, ebi, cur_u, csr_iu, aggB, 6250);
  gemm2_k<128, true, true><<<2 * GG, 256, 0, stream>>>(
      ebi, aggA, WT1i, b1_0, b1_ui, cur_i, hi,
      ebu, aggB, WT1u, b1_0, b1_iu, cur_u, hu, N_USER, GG);

  // ---- layer 2: gather-mean (both dirs), fused double-GEMM -> fp32 out ----
  aggc_k<<<2 * 6250, 256, 0, stream>>>(
      hu, cur_i, csr_ui, aggA, hi, cur_u, csr_iu, aggB, 6250);
  gemm2_k<64, false, false><<<2 * GG, 256, 0, stream>>>(
      hi, aggA, WT2i, b2_0, b2_ui, cur_i, out + (size_t)N_USER * 64,
      hu, aggB, WT2u, b2_0, b2_iu, cur_u, out, N_USER, GG);
}

// Round 13
// 228.251 us; speedup vs baseline: 1.0406x; 1.0406x over previous
//
#include <hip/hip_runtime.h>

#define N_USER 100000
#define N_ITEM 100000
#define NEDGE  500000
#define DEGCAP 32

// setup_k grid sections (after permutation)
#define B_FILL 1954   // 2 x 977 blocks, 512 edges/block (2/thread ILP)
#define B_CONV 12500  // 2 x 6250 fp32->bf16 conversion
#define B_WT   384
#define B_TOT  (B_FILL + B_CONV + B_WT)  // 14838 = 2*3*2473, coprime w/ 7919

typedef __attribute__((ext_vector_type(8))) short short8;
typedef __attribute__((ext_vector_type(4))) float f32x4;

__device__ __forceinline__ unsigned short f2bf(float f) {
  union { float f; unsigned int u; } x{f};
  unsigned int r = x.u + 0x7fffu + ((x.u >> 16) & 1u);  // RTN-even
  return (unsigned short)(r >> 16);
}
__device__ __forceinline__ float bf2f(unsigned short u) {
  union { unsigned int u; float f; } x{(unsigned int)u << 16};
  return x.f;
}

// ---------------------------------------------------------------------------
// setup_k (block-index permuted so latency-bound fill co-runs with streaming):
//  [0,1954)       padded-CSR fill: 2 edges/thread, 2x blocks vs R11 (more
//                 concurrent waves of atomics -> TLP latency hiding).
//                 Plain stores (R11: keep scatter in L2/L3; nontemporal hurt).
//  [1954,14454)   emb fp32 -> bf16 (gather-side copy)
//  [14454,14838)  transposed bf16 weight prep WT[N][256]
// ---------------------------------------------------------------------------
__global__ __launch_bounds__(256) void setup_k(
    const int* __restrict__ src_ui, const int* __restrict__ dst_ui,
    int* __restrict__ cur_i, int* __restrict__ csr_ui,
    const int* __restrict__ src_iu, const int* __restrict__ dst_iu,
    int* __restrict__ cur_u, int* __restrict__ csr_iu,
    const float* __restrict__ emb_u, const float* __restrict__ emb_i,
    unsigned short* __restrict__ ebu, unsigned short* __restrict__ ebi,
    const float* __restrict__ W10, const float* __restrict__ W1ui,
    const float* __restrict__ W1iu, const float* __restrict__ W20,
    const float* __restrict__ W2ui, const float* __restrict__ W2iu,
    unsigned short* __restrict__ WT1i, unsigned short* __restrict__ WT1u,
    unsigned short* __restrict__ WT2i, unsigned short* __restrict__ WT2u) {
  int b = (int)(((unsigned long long)blockIdx.x * 7919ull) % (unsigned long long)B_TOT);
  int tid = threadIdx.x;
  if (b < B_FILL) {
    const int *src, *dst; int *cur, *csr;
    int bb = b;
    if (bb < 977) { src = src_ui; dst = dst_ui; cur = cur_i; csr = csr_ui; }
    else { bb -= 977; src = src_iu; dst = dst_iu; cur = cur_u; csr = csr_iu; }
    int e0 = bb * 512 + tid;
    int d[2], s[2];
    bool ok[2];
#pragma unroll
    for (int k = 0; k < 2; ++k) {
      int e = e0 + k * 256;
      ok[k] = (e < NEDGE);
      d[k] = ok[k] ? dst[e] : 0;
      s[k] = ok[k] ? src[e] : 0;
    }
    int p[2];
#pragma unroll
    for (int k = 0; k < 2; ++k)
      p[k] = ok[k] ? atomicAdd(&cur[d[k]], 1) : DEGCAP;
#pragma unroll
    for (int k = 0; k < 2; ++k)
      if (ok[k] && p[k] < DEGCAP) csr[d[k] * DEGCAP + p[k]] = s[k];
  } else if (b < B_FILL + B_CONV) {
    int blk = b - B_FILL;
    const float* src; unsigned short* dstp;
    if (blk < 6250) { src = emb_u; dstp = ebu; }
    else { blk -= 6250; src = emb_i; dstp = ebi; }
    size_t g = (size_t)blk * 2048 + (size_t)tid * 8;
    float4 x = *(const float4*)(src + g);
    float4 y = *(const float4*)(src + g + 4);
    short8 v{(short)f2bf(x.x), (short)f2bf(x.y), (short)f2bf(x.z), (short)f2bf(x.w),
             (short)f2bf(y.x), (short)f2bf(y.y), (short)f2bf(y.z), (short)f2bf(y.w)};
    *(short8*)(dstp + g) = v;
  } else {
    int t = (b - B_FILL - B_CONV) * 256 + tid;  // 0..98303
    if (t < 32768) {
      int n = t >> 8, k = t & 255;
      float v = (k < 128) ? W10[k * 128 + n] : W1ui[(k - 128) * 128 + n];
      WT1i[t] = f2bf(v);
    } else if (t < 65536) {
      int q = t - 32768; int n = q >> 8, k = q & 255;
      float v = (k < 128) ? W10[k * 128 + n] : W1iu[(k - 128) * 128 + n];
      WT1u[q] = f2bf(v);
    } else if (t < 81920) {
      int q = t - 65536; int n = q >> 8, k = q & 255;
      float v = (k < 128) ? W20[k * 64 + n] : W2ui[(k - 128) * 64 + n];
      WT2i[q] = f2bf(v);
    } else {
      int q = t - 81920; int n = q >> 8, k = q & 255;
      float v = (k < 128) ? W20[k * 64 + n] : W2iu[(k - 128) * 64 + n];
      WT2u[q] = f2bf(v);
    }
  }
}

// ---------------------------------------------------------------------------
// Gather-mean aggregation (bf16, 128-dim), both directions per dispatch.
// Per node (16 lanes): one coalesced 128B csr-row read (int2/lane) into LDS,
// then the x4-unrolled gather pipeline reads indices from LDS (broadcast).
// No LDS staging of features, high occupancy (R5 lesson).
// ---------------------------------------------------------------------------
__global__ __launch_bounds__(256) void aggc_k(
    const unsigned short* __restrict__ featA, const int* __restrict__ curA,
    const int* __restrict__ csrA, unsigned short* __restrict__ outA,
    const unsigned short* __restrict__ featB, const int* __restrict__ curB,
    const int* __restrict__ csrB, unsigned short* __restrict__ outB,
    int nbA) {
  __shared__ int sidx[16][32];
  int b = blockIdx.x;
  const unsigned short* feat; const int* cur; const int* csr; unsigned short* out;
  if (b < nbA) { feat = featA; cur = curA; csr = csrA; out = outA; }
  else { b -= nbA; feat = featB; cur = curB; csr = csrB; out = outB; }
  int grp = threadIdx.x >> 4;
  int ln  = threadIdx.x & 15;
  int node = b * 16 + grp;
  int deg = min(cur[node], DEGCAP);

  int2 sl = *(const int2*)(csr + (size_t)node * DEGCAP + ln * 2);
  sidx[grp][ln * 2] = sl.x;
  sidx[grp][ln * 2 + 1] = sl.y;
  __syncthreads();

  const int* lidx = sidx[grp];
  float a[8] = {0, 0, 0, 0, 0, 0, 0, 0};
  int j = 0;
  if (j + 4 <= deg) {
    int i0 = lidx[0], i1 = lidx[1], i2 = lidx[2], i3 = lidx[3];
    for (;;) {
      bool more = (j + 8 <= deg);
      int n0, n1, n2, n3;
      if (more) { n0 = lidx[j + 4]; n1 = lidx[j + 5]; n2 = lidx[j + 6]; n3 = lidx[j + 7]; }
      short8 v0 = *(const short8*)(feat + (size_t)i0 * 128 + ln * 8);
      short8 v1 = *(const short8*)(feat + (size_t)i1 * 128 + ln * 8);
      short8 v2 = *(const short8*)(feat + (size_t)i2 * 128 + ln * 8);
      short8 v3 = *(const short8*)(feat + (size_t)i3 * 128 + ln * 8);
#pragma unroll
      for (int d = 0; d < 8; ++d)
        a[d] += (bf2f((unsigned short)v0[d]) + bf2f((unsigned short)v1[d])) +
                (bf2f((unsigned short)v2[d]) + bf2f((unsigned short)v3[d]));
      j += 4;
      if (!more) break;
      i0 = n0; i1 = n1; i2 = n2; i3 = n3;
    }
  }
  if (j + 2 <= deg) {
    int i0 = lidx[j], i1 = lidx[j + 1];
    short8 v0 = *(const short8*)(feat + (size_t)i0 * 128 + ln * 8);
    short8 v1 = *(const short8*)(feat + (size_t)i1 * 128 + ln * 8);
#pragma unroll
    for (int d = 0; d < 8; ++d)
      a[d] += bf2f((unsigned short)v0[d]) + bf2f((unsigned short)v1[d]);
    j += 2;
  }
  if (j < deg) {
    short8 v = *(const short8*)(feat + (size_t)lidx[j] * 128 + ln * 8);
#pragma unroll
    for (int d = 0; d < 8; ++d) a[d] += bf2f((unsigned short)v[d]);
  }
  float sc = deg ? 1.f / (float)deg : 0.f;
  short8 pk;
#pragma unroll
  for (int d = 0; d < 8; ++d) pk[d] = (short)f2bf(a[d] * sc);
  *(short8*)(out + (size_t)node * 128 + ln * 8) = pk;
}

// ---------------------------------------------------------------------------
// Fused double-GEMM (bf16 MFMA, fp32 accum), both ntypes per dispatch:
//   out = A1@W[0:128] + A2@W[128:256] + b0 + (deg>0)*be  [, lrelu]
// LDS XOR-swizzled. In-place out==A1 (and gemm2's agg alias in d_out) safe:
// block reads only its own rows, all stage-reads precede epilogue writes.
// ---------------------------------------------------------------------------
template <int N, bool LRELU, bool OUTBF16>
__global__ __launch_bounds__(256) void gemm2_k(
    const unsigned short* __restrict__ A1a, const unsigned short* __restrict__ A2a,
    const unsigned short* __restrict__ WTa, const float* __restrict__ b0a,
    const float* __restrict__ bea, const int* __restrict__ cura,
    void* __restrict__ outa,
    const unsigned short* __restrict__ A1b, const unsigned short* __restrict__ A2b,
    const unsigned short* __restrict__ WTb, const float* __restrict__ b0b,
    const float* __restrict__ beb, const int* __restrict__ curb,
    void* __restrict__ outb, int M, int nbA) {
  constexpr int BM = 64;
  constexpr int CPW = N / 4;
  constexpr int NCF = CPW / 16;
  __shared__ short As[BM * 128];
  __shared__ short Ws[N * 128];
  __shared__ float degmask[BM];

  int blk = blockIdx.x;
  const unsigned short* A1; const unsigned short* A2; const unsigned short* WT;
  const float* b0; const float* be; const int* cur; void* outv;
  if (blk < nbA) { A1 = A1a; A2 = A2a; WT = WTa; b0 = b0a; be = bea; cur = cura; outv = outa; }
  else { blk -= nbA; A1 = A1b; A2 = A2b; WT = WTb; b0 = b0b; be = beb; cur = curb; outv = outb; }

  const int tid = threadIdx.x;
  const int lane = tid & 63;
  const int wave = tid >> 6;
  const int row0 = blk * BM;
  const int colbase = wave * CPW;

  if (tid < BM) {
    int r = row0 + tid;
    degmask[tid] = (r < M && cur[r] > 0) ? 1.f : 0.f;
  }

  f32x4 acc[4][NCF] = {};

#pragma unroll
  for (int kh = 0; kh < 2; ++kh) {
    __syncthreads();
    const unsigned short* base = (kh == 0) ? A1 : A2;
#pragma unroll
    for (int it = 0; it < 4; ++it) {
      int chunk = tid + it * 256;
      int row = chunk >> 4, c16 = chunk & 15;
      int gr = row0 + row; if (gr > M - 1) gr = M - 1;
      short8 v = *(const short8*)(base + (size_t)gr * 128 + c16 * 8);
      int byteoff = row * 256 + ((c16 * 16) ^ ((row & 7) << 4));
      *(short8*)((char*)As + byteoff) = v;
    }
#pragma unroll
    for (int it = 0; it < (N * 16) / 256; ++it) {
      int chunk = tid + it * 256;
      int n = chunk >> 4, c16 = chunk & 15;
      short8 v = *(const short8*)(WT + (size_t)n * 256 + kh * 128 + c16 * 8);
      int byteoff = n * 256 + ((c16 * 16) ^ ((n & 7) << 4));
      *(short8*)((char*)Ws + byteoff) = v;
    }
    __syncthreads();

#pragma unroll
    for (int ks = 0; ks < 4; ++ks) {
      short8 af[4];
#pragma unroll
      for (int rf = 0; rf < 4; ++rf) {
        int row = rf * 16 + (lane & 15);
        int c16 = ks * 4 + (lane >> 4);
        int byteoff = row * 256 + ((c16 * 16) ^ ((row & 7) << 4));
        af[rf] = *(const short8*)((const char*)As + byteoff);
      }
      short8 wf[NCF];
#pragma unroll
      for (int cf = 0; cf < NCF; ++cf) {
        int n = colbase + cf * 16 + (lane & 15);
        int c16 = ks * 4 + (lane >> 4);
        int byteoff = n * 256 + ((c16 * 16) ^ ((n & 7) << 4));
        wf[cf] = *(const short8*)((const char*)Ws + byteoff);
      }
#pragma unroll
      for (int rf = 0; rf < 4; ++rf)
#pragma unroll
        for (int cf = 0; cf < NCF; ++cf)
          acc[rf][cf] = __builtin_amdgcn_mfma_f32_16x16x32_bf16(
              af[rf], wf[cf], acc[rf][cf], 0, 0, 0);
    }
  }

  // C/D layout: col=lane&15, row=(lane>>4)*4+j  [m89 verified]
#pragma unroll
  for (int cf = 0; cf < NCF; ++cf) {
    int c = colbase + cf * 16 + (lane & 15);
    float bb0 = b0[c], bbe = be[c];
#pragma unroll
    for (int rf = 0; rf < 4; ++rf) {
#pragma unroll
      for (int j = 0; j < 4; ++j) {
        int lr = rf * 16 + (lane >> 4) * 4 + j;
        int r = row0 + lr;
        if (r < M) {
          float v = acc[rf][cf][j] + bb0 + degmask[lr] * bbe;
          if (LRELU) v = (v >= 0.f) ? v : 0.01f * v;
          if (OUTBF16)
            ((unsigned short*)outv)[(size_t)r * N + c] = f2bf(v);
          else
            ((float*)outv)[(size_t)r * N + c] = v;
        }
      }
    }
  }
}

extern "C" void kernel_launch(void* const* d_in, const int* in_sizes, int n_in,
                              void* d_out, int out_size, void* d_ws,
                              size_t ws_size, hipStream_t stream) {
  const float* emb_u = (const float*)d_in[0];
  const float* emb_i = (const float*)d_in[1];
  const float* W1_0  = (const float*)d_in[2];
  const float* b1_0  = (const float*)d_in[3];
  const float* W1_ui = (const float*)d_in[4];
  const float* b1_ui = (const float*)d_in[5];
  const float* W1_iu = (const float*)d_in[6];
  const float* b1_iu = (const float*)d_in[7];
  const float* W2_0  = (const float*)d_in[8];
  const float* b2_0  = (const float*)d_in[9];
  const float* W2_ui = (const float*)d_in[10];
  const float* b2_ui = (const float*)d_in[11];
  const float* W2_iu = (const float*)d_in[12];
  const float* b2_iu = (const float*)d_in[13];
  const int* src_ui = (const int*)d_in[14];
  const int* dst_ui = (const int*)d_in[15];
  const int* src_iu = (const int*)d_in[16];
  const int* dst_iu = (const int*)d_in[17];
  float* out = (float*)d_out;

  // ---- workspace layout (~78 MB) ----
  char* p = (char*)d_ws;
  unsigned short* WT1i = (unsigned short*)p; p += 65536;
  unsigned short* WT1u = (unsigned short*)p; p += 65536;
  unsigned short* WT2i = (unsigned short*)p; p += 32768;
  unsigned short* WT2u = (unsigned short*)p; p += 32768;
  int* cur_i = (int*)p; p += 400128;
  int* cur_u = (int*)p; p += 400128;
  int* csr_ui = (int*)p; p += (size_t)100032 * DEGCAP * 4;  // 12.8 MB
  int* csr_iu = (int*)p; p += (size_t)100032 * DEGCAP * 4;
  const size_t FB = (size_t)N_USER * 128 * 2;        // 25.6 MB
  unsigned short* ebu  = (unsigned short*)p; p += FB;  // -> hu (in place)
  unsigned short* ebi  = (unsigned short*)p; p += FB;  // -> hi (in place)
  unsigned short* hu = ebu;
  unsigned short* hi = ebi;
  // agg buffers alias d_out (dead until gemm2, which reads each agg row
  // then overwrites the identical bytes; read-before-write within block,
  // disjoint rows across blocks):
  unsigned short* aggB = (unsigned short*)out;                          // user
  unsigned short* aggA = (unsigned short*)(out + (size_t)N_USER * 64);  // item

  const int GG = (N_USER + 63) / 64;  // 1563

  hipMemsetAsync(cur_i, 0, 2 * 400128, stream);
  setup_k<<<B_TOT, 256, 0, stream>>>(src_ui, dst_ui, cur_i, csr_ui,
                                     src_iu, dst_iu, cur_u, csr_iu,
                                     emb_u, emb_i, ebu, ebi,
                                     W1_0, W1_ui, W1_iu, W2_0, W2_ui, W2_iu,
                                     WT1i, WT1u, WT2i, WT2u);

  // ---- layer 1: gather-mean (both dirs), fused double-GEMM + lrelu ----
  aggc_k<<<2 * 6250, 256, 0, stream>>>(
      ebu, cur_i, csr_ui, aggA, ebi, cur_u, csr_iu, aggB, 6250);
  gemm2_k<128, true, true><<<2 * GG, 256, 0, stream>>>(
      ebi, aggA, WT1i, b1_0, b1_ui, cur_i, hi,
      ebu, aggB, WT1u, b1_0, b1_iu, cur_u, hu, N_USER, GG);

  // ---- layer 2: gather-mean (both dirs), fused double-GEMM -> fp32 out ----
  aggc_k<<<2 * 6250, 256, 0, stream>>>(
      hu, cur_i, csr_ui, aggA, hi, cur_u, csr_iu, aggB, 6250);
  gemm2_k<64, false, false><<<2 * GG, 256, 0, stream>>>(
      hi, aggA, WT2i, b2_0, b2_ui, cur_i, out + (size_t)N_USER * 64,
      hu, aggB, WT2u, b2_0, b2_iu, cur_u, out, N_USER, GG);
}

// Round 14
// 225.873 us; speedup vs baseline: 1.0515x; 1.0105x over previous
//
#include <hip/hip_runtime.h>

#define N_USER 100000
#define N_ITEM 100000
#define NEDGE  500000
#define DEGCAP 32

// setup_k grid roles (raw order — fill blocks launch FIRST, conversions
// stream behind them on the same CUs):
#define B_FILL 256
#define B_CONV 12500
#define B_WT   384
#define B_TOT  (B_FILL + B_CONV + B_WT)  // 13140

typedef __attribute__((ext_vector_type(8))) short short8;
typedef __attribute__((ext_vector_type(4))) float f32x4;

__device__ __forceinline__ unsigned short f2bf(float f) {
  union { float f; unsigned int u; } x{f};
  unsigned int r = x.u + 0x7fffu + ((x.u >> 16) & 1u);  // RTN-even
  return (unsigned short)(r >> 16);
}
__device__ __forceinline__ float bf2f(unsigned short u) {
  union { unsigned int u; float f; } x{(unsigned int)u << 16};
  return x.f;
}

// ---------------------------------------------------------------------------
// setup_k:
//  [0,256)        deep-queue padded-CSR fill: each block owns a 4096-edge
//                 chunk of the concatenated 1M edges (both graphs), 4 batches
//                 x 4 independent edges/thread -> ~262K atomic chains
//                 sustained (2x R13). Launched first; conversion blocks
//                 co-occupy the CUs from t=0 and hide the atomic latency.
//  [256,12756)    emb fp32 -> bf16 (gather-side copy)
//  [12756,13140)  transposed bf16 weight prep WT[N][256]
// ---------------------------------------------------------------------------
__global__ __launch_bounds__(256) void setup_k(
    const int* __restrict__ src_ui, const int* __restrict__ dst_ui,
    int* __restrict__ cur_i, int* __restrict__ csr_ui,
    const int* __restrict__ src_iu, const int* __restrict__ dst_iu,
    int* __restrict__ cur_u, int* __restrict__ csr_iu,
    const float* __restrict__ emb_u, const float* __restrict__ emb_i,
    unsigned short* __restrict__ ebu, unsigned short* __restrict__ ebi,
    const float* __restrict__ W10, const float* __restrict__ W1ui,
    const float* __restrict__ W1iu, const float* __restrict__ W20,
    const float* __restrict__ W2ui, const float* __restrict__ W2iu,
    unsigned short* __restrict__ WT1i, unsigned short* __restrict__ WT1u,
    unsigned short* __restrict__ WT2i, unsigned short* __restrict__ WT2u) {
  int b = blockIdx.x, tid = threadIdx.x;
  if (b < B_FILL) {
    int chunk = b * 4096;
#pragma unroll 1
    for (int it = 0; it < 4; ++it) {
      int e0 = chunk + it * 1024 + tid;
      int d[4], s[4];
      int* curp[4]; int* csrp[4];
      bool ok[4];
#pragma unroll
      for (int k = 0; k < 4; ++k) {
        int e = e0 + k * 256;
        ok[k] = (e < 2 * NEDGE);
        bool g0 = (e < NEDGE);
        int ee = g0 ? e : e - NEDGE;
        const int* dp = g0 ? dst_ui : dst_iu;
        const int* sp = g0 ? src_ui : src_iu;
        curp[k] = g0 ? cur_i : cur_u;
        csrp[k] = g0 ? csr_ui : csr_iu;
        d[k] = ok[k] ? dp[ee] : 0;
        s[k] = ok[k] ? sp[ee] : 0;
      }
      int p[4];
#pragma unroll
      for (int k = 0; k < 4; ++k)
        p[k] = ok[k] ? atomicAdd(&curp[k][d[k]], 1) : DEGCAP;
#pragma unroll
      for (int k = 0; k < 4; ++k)
        if (ok[k] && p[k] < DEGCAP) csrp[k][d[k] * DEGCAP + p[k]] = s[k];
    }
  } else if (b < B_FILL + B_CONV) {
    int blk = b - B_FILL;
    const float* src; unsigned short* dstp;
    if (blk < 6250) { src = emb_u; dstp = ebu; }
    else { blk -= 6250; src = emb_i; dstp = ebi; }
    size_t g = (size_t)blk * 2048 + (size_t)tid * 8;
    float4 x = *(const float4*)(src + g);
    float4 y = *(const float4*)(src + g + 4);
    short8 v{(short)f2bf(x.x), (short)f2bf(x.y), (short)f2bf(x.z), (short)f2bf(x.w),
             (short)f2bf(y.x), (short)f2bf(y.y), (short)f2bf(y.z), (short)f2bf(y.w)};
    *(short8*)(dstp + g) = v;
  } else {
    int t = (b - B_FILL - B_CONV) * 256 + tid;  // 0..98303
    if (t < 32768) {
      int n = t >> 8, k = t & 255;
      float v = (k < 128) ? W10[k * 128 + n] : W1ui[(k - 128) * 128 + n];
      WT1i[t] = f2bf(v);
    } else if (t < 65536) {
      int q = t - 32768; int n = q >> 8, k = q & 255;
      float v = (k < 128) ? W10[k * 128 + n] : W1iu[(k - 128) * 128 + n];
      WT1u[q] = f2bf(v);
    } else if (t < 81920) {
      int q = t - 65536; int n = q >> 8, k = q & 255;
      float v = (k < 128) ? W20[k * 64 + n] : W2ui[(k - 128) * 64 + n];
      WT2i[q] = f2bf(v);
    } else {
      int q = t - 81920; int n = q >> 8, k = q & 255;
      float v = (k < 128) ? W20[k * 64 + n] : W2iu[(k - 128) * 64 + n];
      WT2u[q] = f2bf(v);
    }
  }
}

// ---------------------------------------------------------------------------
// Gather-mean aggregation (bf16, 128-dim), both directions per dispatch.
// Per node (16 lanes): one coalesced 128B csr-row read (int2/lane) into LDS,
// then the x4-unrolled gather pipeline reads indices from LDS (broadcast).
// No LDS staging of features, high occupancy (R5 lesson).
// ---------------------------------------------------------------------------
__global__ __launch_bounds__(256) void aggc_k(
    const unsigned short* __restrict__ featA, const int* __restrict__ curA,
    const int* __restrict__ csrA, unsigned short* __restrict__ outA,
    const unsigned short* __restrict__ featB, const int* __restrict__ curB,
    const int* __restrict__ csrB, unsigned short* __restrict__ outB,
    int nbA) {
  __shared__ int sidx[16][32];
  int b = blockIdx.x;
  const unsigned short* feat; const int* cur; const int* csr; unsigned short* out;
  if (b < nbA) { feat = featA; cur = curA; csr = csrA; out = outA; }
  else { b -= nbA; feat = featB; cur = curB; csr = csrB; out = outB; }
  int grp = threadIdx.x >> 4;
  int ln  = threadIdx.x & 15;
  int node = b * 16 + grp;
  int deg = min(cur[node], DEGCAP);

  int2 sl = *(const int2*)(csr + (size_t)node * DEGCAP + ln * 2);
  sidx[grp][ln * 2] = sl.x;
  sidx[grp][ln * 2 + 1] = sl.y;
  __syncthreads();

  const int* lidx = sidx[grp];
  float a[8] = {0, 0, 0, 0, 0, 0, 0, 0};
  int j = 0;
  if (j + 4 <= deg) {
    int i0 = lidx[0], i1 = lidx[1], i2 = lidx[2], i3 = lidx[3];
    for (;;) {
      bool more = (j + 8 <= deg);
      int n0, n1, n2, n3;
      if (more) { n0 = lidx[j + 4]; n1 = lidx[j + 5]; n2 = lidx[j + 6]; n3 = lidx[j + 7]; }
      short8 v0 = *(const short8*)(feat + (size_t)i0 * 128 + ln * 8);
      short8 v1 = *(const short8*)(feat + (size_t)i1 * 128 + ln * 8);
      short8 v2 = *(const short8*)(feat + (size_t)i2 * 128 + ln * 8);
      short8 v3 = *(const short8*)(feat + (size_t)i3 * 128 + ln * 8);
#pragma unroll
      for (int d = 0; d < 8; ++d)
        a[d] += (bf2f((unsigned short)v0[d]) + bf2f((unsigned short)v1[d])) +
                (bf2f((unsigned short)v2[d]) + bf2f((unsigned short)v3[d]));
      j += 4;
      if (!more) break;
      i0 = n0; i1 = n1; i2 = n2; i3 = n3;
    }
  }
  if (j + 2 <= deg) {
    int i0 = lidx[j], i1 = lidx[j + 1];
    short8 v0 = *(const short8*)(feat + (size_t)i0 * 128 + ln * 8);
    short8 v1 = *(const short8*)(feat + (size_t)i1 * 128 + ln * 8);
#pragma unroll
    for (int d = 0; d < 8; ++d)
      a[d] += bf2f((unsigned short)v0[d]) + bf2f((unsigned short)v1[d]);
    j += 2;
  }
  if (j < deg) {
    short8 v = *(const short8*)(feat + (size_t)lidx[j] * 128 + ln * 8);
#pragma unroll
    for (int d = 0; d < 8; ++d) a[d] += bf2f((unsigned short)v[d]);
  }
  float sc = deg ? 1.f / (float)deg : 0.f;
  short8 pk;
#pragma unroll
  for (int d = 0; d < 8; ++d) pk[d] = (short)f2bf(a[d] * sc);
  *(short8*)(out + (size_t)node * 128 + ln * 8) = pk;
}

// ---------------------------------------------------------------------------
// Fused double-GEMM (bf16 MFMA, fp32 accum), both ntypes per dispatch:
//   out = A1@W[0:128] + A2@W[128:256] + b0 + (deg>0)*be  [, lrelu]
// Software-pipelined: BOTH kh A-tile chunks are loaded into registers at
// kernel start (all HBM loads in flight before the first barrier); LDS
// staging then consumes registers. LDS XOR-swizzled. In-place out==A1
// (and agg alias in d_out) safe: block reads only its own rows, all
// stage-reads (here: register loads) precede epilogue writes.
// ---------------------------------------------------------------------------
template <int N, bool LRELU, bool OUTBF16>
__global__ __launch_bounds__(256) void gemm2_k(
    const unsigned short* __restrict__ A1a, const unsigned short* __restrict__ A2a,
    const unsigned short* __restrict__ WTa, const float* __restrict__ b0a,
    const float* __restrict__ bea, const int* __restrict__ cura,
    void* __restrict__ outa,
    const unsigned short* __restrict__ A1b, const unsigned short* __restrict__ A2b,
    const unsigned short* __restrict__ WTb, const float* __restrict__ b0b,
    const float* __restrict__ beb, const int* __restrict__ curb,
    void* __restrict__ outb, int M, int nbA) {
  constexpr int BM = 64;
  constexpr int CPW = N / 4;
  constexpr int NCF = CPW / 16;
  __shared__ short As[BM * 128];
  __shared__ short Ws[N * 128];
  __shared__ float degmask[BM];

  int blk = blockIdx.x;
  const unsigned short* A1; const unsigned short* A2; const unsigned short* WT;
  const float* b0; const float* be; const int* cur; void* outv;
  if (blk < nbA) { A1 = A1a; A2 = A2a; WT = WTa; b0 = b0a; be = bea; cur = cura; outv = outa; }
  else { blk -= nbA; A1 = A1b; A2 = A2b; WT = WTb; b0 = b0b; be = beb; cur = curb; outv = outb; }

  const int tid = threadIdx.x;
  const int lane = tid & 63;
  const int wave = tid >> 6;
  const int row0 = blk * BM;
  const int colbase = wave * CPW;

  // hoist ALL A-tile global loads (both kh halves) before any barrier
  short8 aA[4], aB[4];
#pragma unroll
  for (int it = 0; it < 4; ++it) {
    int chunk = tid + it * 256;
    int row = chunk >> 4, c16 = chunk & 15;
    int gr = row0 + row; if (gr > M - 1) gr = M - 1;
    aA[it] = *(const short8*)(A1 + (size_t)gr * 128 + c16 * 8);
    aB[it] = *(const short8*)(A2 + (size_t)gr * 128 + c16 * 8);
  }

  if (tid < BM) {
    int r = row0 + tid;
    degmask[tid] = (r < M && cur[r] > 0) ? 1.f : 0.f;
  }

  f32x4 acc[4][NCF] = {};

#pragma unroll
  for (int kh = 0; kh < 2; ++kh) {
    __syncthreads();
#pragma unroll
    for (int it = 0; it < 4; ++it) {
      int chunk = tid + it * 256;
      int row = chunk >> 4, c16 = chunk & 15;
      int byteoff = row * 256 + ((c16 * 16) ^ ((row & 7) << 4));
      *(short8*)((char*)As + byteoff) = (kh == 0) ? aA[it] : aB[it];
    }
#pragma unroll
    for (int it = 0; it < (N * 16) / 256; ++it) {
      int chunk = tid + it * 256;
      int n = chunk >> 4, c16 = chunk & 15;
      short8 v = *(const short8*)(WT + (size_t)n * 256 + kh * 128 + c16 * 8);
      int byteoff = n * 256 + ((c16 * 16) ^ ((n & 7) << 4));
      *(short8*)((char*)Ws + byteoff) = v;
    }
    __syncthreads();

#pragma unroll
    for (int ks = 0; ks < 4; ++ks) {
      short8 af[4];
#pragma unroll
      for (int rf = 0; rf < 4; ++rf) {
        int row = rf * 16 + (lane & 15);
        int c16 = ks * 4 + (lane >> 4);
        int byteoff = row * 256 + ((c16 * 16) ^ ((row & 7) << 4));
        af[rf] = *(const short8*)((const char*)As + byteoff);
      }
      short8 wf[NCF];
#pragma unroll
      for (int cf = 0; cf < NCF; ++cf) {
        int n = colbase + cf * 16 + (lane & 15);
        int c16 = ks * 4 + (lane >> 4);
        int byteoff = n * 256 + ((c16 * 16) ^ ((n & 7) << 4));
        wf[cf] = *(const short8*)((const char*)Ws + byteoff);
      }
#pragma unroll
      for (int rf = 0; rf < 4; ++rf)
#pragma unroll
        for (int cf = 0; cf < NCF; ++cf)
          acc[rf][cf] = __builtin_amdgcn_mfma_f32_16x16x32_bf16(
              af[rf], wf[cf], acc[rf][cf], 0, 0, 0);
    }
  }

  // C/D layout: col=lane&15, row=(lane>>4)*4+j  [m89 verified]
#pragma unroll
  for (int cf = 0; cf < NCF; ++cf) {
    int c = colbase + cf * 16 + (lane & 15);
    float bb0 = b0[c], bbe = be[c];
#pragma unroll
    for (int rf = 0; rf < 4; ++rf) {
#pragma unroll
      for (int j = 0; j < 4; ++j) {
        int lr = rf * 16 + (lane >> 4) * 4 + j;
        int r = row0 + lr;
        if (r < M) {
          float v = acc[rf][cf][j] + bb0 + degmask[lr] * bbe;
          if (LRELU) v = (v >= 0.f) ? v : 0.01f * v;
          if (OUTBF16)
            ((unsigned short*)outv)[(size_t)r * N + c] = f2bf(v);
          else
            ((float*)outv)[(size_t)r * N + c] = v;
        }
      }
    }
  }
}

extern "C" void kernel_launch(void* const* d_in, const int* in_sizes, int n_in,
                              void* d_out, int out_size, void* d_ws,
                              size_t ws_size, hipStream_t stream) {
  const float* emb_u = (const float*)d_in[0];
  const float* emb_i = (const float*)d_in[1];
  const float* W1_0  = (const float*)d_in[2];
  const float* b1_0  = (const float*)d_in[3];
  const float* W1_ui = (const float*)d_in[4];
  const float* b1_ui = (const float*)d_in[5];
  const float* W1_iu = (const float*)d_in[6];
  const float* b1_iu = (const float*)d_in[7];
  const float* W2_0  = (const float*)d_in[8];
  const float* b2_0  = (const float*)d_in[9];
  const float* W2_ui = (const float*)d_in[10];
  const float* b2_ui = (const float*)d_in[11];
  const float* W2_iu = (const float*)d_in[12];
  const float* b2_iu = (const float*)d_in[13];
  const int* src_ui = (const int*)d_in[14];
  const int* dst_ui = (const int*)d_in[15];
  const int* src_iu = (const int*)d_in[16];
  const int* dst_iu = (const int*)d_in[17];
  float* out = (float*)d_out;

  // ---- workspace layout (~78 MB) ----
  char* p = (char*)d_ws;
  unsigned short* WT1i = (unsigned short*)p; p += 65536;
  unsigned short* WT1u = (unsigned short*)p; p += 65536;
  unsigned short* WT2i = (unsigned short*)p; p += 32768;
  unsigned short* WT2u = (unsigned short*)p; p += 32768;
  int* cur_i = (int*)p; p += 400128;
  int* cur_u = (int*)p; p += 400128;
  int* csr_ui = (int*)p; p += (size_t)100032 * DEGCAP * 4;  // 12.8 MB
  int* csr_iu = (int*)p; p += (size_t)100032 * DEGCAP * 4;
  const size_t FB = (size_t)N_USER * 128 * 2;        // 25.6 MB
  unsigned short* ebu  = (unsigned short*)p; p += FB;  // -> hu (in place)
  unsigned short* ebi  = (unsigned short*)p; p += FB;  // -> hi (in place)
  unsigned short* hu = ebu;
  unsigned short* hi = ebi;
  // agg buffers alias d_out (dead until gemm2, which reads each agg row
  // then overwrites the identical bytes; read-before-write within block,
  // disjoint rows across blocks):
  unsigned short* aggB = (unsigned short*)out;                          // user
  unsigned short* aggA = (unsigned short*)(out + (size_t)N_USER * 64);  // item

  const int GG = (N_USER + 63) / 64;  // 1563

  hipMemsetAsync(cur_i, 0, 2 * 400128, stream);
  setup_k<<<B_TOT, 256, 0, stream>>>(src_ui, dst_ui, cur_i, csr_ui,
                                     src_iu, dst_iu, cur_u, csr_iu,
                                     emb_u, emb_i, ebu, ebi,
                                     W1_0, W1_ui, W1_iu, W2_0, W2_ui, W2_iu,
                                     WT1i, WT1u, WT2i, WT2u);

  // ---- layer 1: gather-mean (both dirs), fused double-GEMM + lrelu ----
  aggc_k<<<2 * 6250, 256, 0, stream>>>(
      ebu, cur_i, csr_ui, aggA, ebi, cur_u, csr_iu, aggB, 6250);
  gemm2_k<128, true, true><<<2 * GG, 256, 0, stream>>>(
      ebi, aggA, WT1i, b1_0, b1_ui, cur_i, hi,
      ebu, aggB, WT1u, b1_0, b1_iu, cur_u, hu, N_USER, GG);

  // ---- layer 2: gather-mean (both dirs), fused double-GEMM -> fp32 out ----
  aggc_k<<<2 * 6250, 256, 0, stream>>>(
      hu, cur_i, csr_ui, aggA, hi, cur_u, csr_iu, aggB, 6250);
  gemm2_k<64, false, false><<<2 * GG, 256, 0, stream>>>(
      hi, aggA, WT2i, b2_0, b2_ui, cur_i, out + (size_t)N_USER * 64,
      hu, aggB, WT2u, b2_0, b2_iu, cur_u, out, N_USER, GG);
}

// Round 15
// 225.633 us; speedup vs baseline: 1.0526x; 1.0011x over previous
//
#include <hip/hip_runtime.h>

#define N_USER 100000
#define N_ITEM 100000
#define NEDGE  500000
#define DEGCAP 32

// setup_k grid roles (raw order — fill blocks launch FIRST, conversions
// stream behind them on the same CUs):
#define B_FILL 256
#define B_CONV 12500
#define B_WT   384
#define B_TOT  (B_FILL + B_CONV + B_WT)  // 13140

typedef __attribute__((ext_vector_type(8))) short short8;
typedef __attribute__((ext_vector_type(4))) short short4_t;
typedef __attribute__((ext_vector_type(4))) float f32x4;

__device__ __forceinline__ unsigned short f2bf(float f) {
  union { float f; unsigned int u; } x{f};
  unsigned int r = x.u + 0x7fffu + ((x.u >> 16) & 1u);  // RTN-even
  return (unsigned short)(r >> 16);
}
__device__ __forceinline__ float bf2f(unsigned short u) {
  union { unsigned int u; float f; } x{(unsigned int)u << 16};
  return x.f;
}

// ---------------------------------------------------------------------------
// setup_k (unchanged from R14 — fill is at its atomic-service floor):
//  [0,256) deep-queue padded-CSR fill; [256,12756) emb fp32->bf16;
//  [12756,13140) transposed bf16 weight prep WT[N][256].
// ---------------------------------------------------------------------------
__global__ __launch_bounds__(256) void setup_k(
    const int* __restrict__ src_ui, const int* __restrict__ dst_ui,
    int* __restrict__ cur_i, int* __restrict__ csr_ui,
    const int* __restrict__ src_iu, const int* __restrict__ dst_iu,
    int* __restrict__ cur_u, int* __restrict__ csr_iu,
    const float* __restrict__ emb_u, const float* __restrict__ emb_i,
    unsigned short* __restrict__ ebu, unsigned short* __restrict__ ebi,
    const float* __restrict__ W10, const float* __restrict__ W1ui,
    const float* __restrict__ W1iu, const float* __restrict__ W20,
    const float* __restrict__ W2ui, const float* __restrict__ W2iu,
    unsigned short* __restrict__ WT1i, unsigned short* __restrict__ WT1u,
    unsigned short* __restrict__ WT2i, unsigned short* __restrict__ WT2u) {
  int b = blockIdx.x, tid = threadIdx.x;
  if (b < B_FILL) {
    int chunk = b * 4096;
#pragma unroll 1
    for (int it = 0; it < 4; ++it) {
      int e0 = chunk + it * 1024 + tid;
      int d[4], s[4];
      int* curp[4]; int* csrp[4];
      bool ok[4];
#pragma unroll
      for (int k = 0; k < 4; ++k) {
        int e = e0 + k * 256;
        ok[k] = (e < 2 * NEDGE);
        bool g0 = (e < NEDGE);
        int ee = g0 ? e : e - NEDGE;
        const int* dp = g0 ? dst_ui : dst_iu;
        const int* sp = g0 ? src_ui : src_iu;
        curp[k] = g0 ? cur_i : cur_u;
        csrp[k] = g0 ? csr_ui : csr_iu;
        d[k] = ok[k] ? dp[ee] : 0;
        s[k] = ok[k] ? sp[ee] : 0;
      }
      int p[4];
#pragma unroll
      for (int k = 0; k < 4; ++k)
        p[k] = ok[k] ? atomicAdd(&curp[k][d[k]], 1) : DEGCAP;
#pragma unroll
      for (int k = 0; k < 4; ++k)
        if (ok[k] && p[k] < DEGCAP) csrp[k][d[k] * DEGCAP + p[k]] = s[k];
    }
  } else if (b < B_FILL + B_CONV) {
    int blk = b - B_FILL;
    const float* src; unsigned short* dstp;
    if (blk < 6250) { src = emb_u; dstp = ebu; }
    else { blk -= 6250; src = emb_i; dstp = ebi; }
    size_t g = (size_t)blk * 2048 + (size_t)tid * 8;
    float4 x = *(const float4*)(src + g);
    float4 y = *(const float4*)(src + g + 4);
    short8 v{(short)f2bf(x.x), (short)f2bf(x.y), (short)f2bf(x.z), (short)f2bf(x.w),
             (short)f2bf(y.x), (short)f2bf(y.y), (short)f2bf(y.z), (short)f2bf(y.w)};
    *(short8*)(dstp + g) = v;
  } else {
    int t = (b - B_FILL - B_CONV) * 256 + tid;  // 0..98303
    if (t < 32768) {
      int n = t >> 8, k = t & 255;
      float v = (k < 128) ? W10[k * 128 + n] : W1ui[(k - 128) * 128 + n];
      WT1i[t] = f2bf(v);
    } else if (t < 65536) {
      int q = t - 32768; int n = q >> 8, k = q & 255;
      float v = (k < 128) ? W10[k * 128 + n] : W1iu[(k - 128) * 128 + n];
      WT1u[q] = f2bf(v);
    } else if (t < 81920) {
      int q = t - 65536; int n = q >> 8, k = q & 255;
      float v = (k < 128) ? W20[k * 64 + n] : W2ui[(k - 128) * 64 + n];
      WT2i[q] = f2bf(v);
    } else {
      int q = t - 81920; int n = q >> 8, k = q & 255;
      float v = (k < 128) ? W20[k * 64 + n] : W2iu[(k - 128) * 64 + n];
      WT2u[q] = f2bf(v);
    }
  }
}

// ---------------------------------------------------------------------------
// Gather-mean over 128-dim bf16 rows (layer 1), both directions per
// dispatch. 16 lanes/node (short8/lane), csr row staged to LDS. (R14)
// ---------------------------------------------------------------------------
__global__ __launch_bounds__(256) void aggc_k(
    const unsigned short* __restrict__ featA, const int* __restrict__ curA,
    const int* __restrict__ csrA, unsigned short* __restrict__ outA,
    const unsigned short* __restrict__ featB, const int* __restrict__ curB,
    const int* __restrict__ csrB, unsigned short* __restrict__ outB,
    int nbA) {
  __shared__ int sidx[16][32];
  int b = blockIdx.x;
  const unsigned short* feat; const int* cur; const int* csr; unsigned short* out;
  if (b < nbA) { feat = featA; cur = curA; csr = csrA; out = outA; }
  else { b -= nbA; feat = featB; cur = curB; csr = csrB; out = outB; }
  int grp = threadIdx.x >> 4;
  int ln  = threadIdx.x & 15;
  int node = b * 16 + grp;
  int deg = min(cur[node], DEGCAP);

  int2 sl = *(const int2*)(csr + (size_t)node * DEGCAP + ln * 2);
  sidx[grp][ln * 2] = sl.x;
  sidx[grp][ln * 2 + 1] = sl.y;
  __syncthreads();

  const int* lidx = sidx[grp];
  float a[8] = {0, 0, 0, 0, 0, 0, 0, 0};
  int j = 0;
  if (j + 4 <= deg) {
    int i0 = lidx[0], i1 = lidx[1], i2 = lidx[2], i3 = lidx[3];
    for (;;) {
      bool more = (j + 8 <= deg);
      int n0, n1, n2, n3;
      if (more) { n0 = lidx[j + 4]; n1 = lidx[j + 5]; n2 = lidx[j + 6]; n3 = lidx[j + 7]; }
      short8 v0 = *(const short8*)(feat + (size_t)i0 * 128 + ln * 8);
      short8 v1 = *(const short8*)(feat + (size_t)i1 * 128 + ln * 8);
      short8 v2 = *(const short8*)(feat + (size_t)i2 * 128 + ln * 8);
      short8 v3 = *(const short8*)(feat + (size_t)i3 * 128 + ln * 8);
#pragma unroll
      for (int d = 0; d < 8; ++d)
        a[d] += (bf2f((unsigned short)v0[d]) + bf2f((unsigned short)v1[d])) +
                (bf2f((unsigned short)v2[d]) + bf2f((unsigned short)v3[d]));
      j += 4;
      if (!more) break;
      i0 = n0; i1 = n1; i2 = n2; i3 = n3;
    }
  }
  if (j + 2 <= deg) {
    int i0 = lidx[j], i1 = lidx[j + 1];
    short8 v0 = *(const short8*)(feat + (size_t)i0 * 128 + ln * 8);
    short8 v1 = *(const short8*)(feat + (size_t)i1 * 128 + ln * 8);
#pragma unroll
    for (int d = 0; d < 8; ++d)
      a[d] += bf2f((unsigned short)v0[d]) + bf2f((unsigned short)v1[d]);
    j += 2;
  }
  if (j < deg) {
    short8 v = *(const short8*)(feat + (size_t)lidx[j] * 128 + ln * 8);
#pragma unroll
    for (int d = 0; d < 8; ++d) a[d] += bf2f((unsigned short)v[d]);
  }
  float sc = deg ? 1.f / (float)deg : 0.f;
  short8 pk;
#pragma unroll
  for (int d = 0; d < 8; ++d) pk[d] = (short)f2bf(a[d] * sc);
  *(short8*)(out + (size_t)node * 128 + ln * 8) = pk;
}

// ---------------------------------------------------------------------------
// Gather-mean over 64-dim bf16 rows (layer 2 wh2), both directions.
// 16 lanes/node, short4 (8B)/lane -> 128B row.
// ---------------------------------------------------------------------------
__global__ __launch_bounds__(256) void agg64_k(
    const unsigned short* __restrict__ featA, const int* __restrict__ curA,
    const int* __restrict__ csrA, unsigned short* __restrict__ outA,
    const unsigned short* __restrict__ featB, const int* __restrict__ curB,
    const int* __restrict__ csrB, unsigned short* __restrict__ outB,
    int nbA) {
  __shared__ int sidx[16][32];
  int b = blockIdx.x;
  const unsigned short* feat; const int* cur; const int* csr; unsigned short* out;
  if (b < nbA) { feat = featA; cur = curA; csr = csrA; out = outA; }
  else { b -= nbA; feat = featB; cur = curB; csr = csrB; out = outB; }
  int grp = threadIdx.x >> 4;
  int ln  = threadIdx.x & 15;
  int node = b * 16 + grp;
  int deg = min(cur[node], DEGCAP);

  int2 sl = *(const int2*)(csr + (size_t)node * DEGCAP + ln * 2);
  sidx[grp][ln * 2] = sl.x;
  sidx[grp][ln * 2 + 1] = sl.y;
  __syncthreads();

  const int* lidx = sidx[grp];
  float a[4] = {0, 0, 0, 0};
  int j = 0;
  if (j + 4 <= deg) {
    int i0 = lidx[0], i1 = lidx[1], i2 = lidx[2], i3 = lidx[3];
    for (;;) {
      bool more = (j + 8 <= deg);
      int n0, n1, n2, n3;
      if (more) { n0 = lidx[j + 4]; n1 = lidx[j + 5]; n2 = lidx[j + 6]; n3 = lidx[j + 7]; }
      short4_t v0 = *(const short4_t*)(feat + (size_t)i0 * 64 + ln * 4);
      short4_t v1 = *(const short4_t*)(feat + (size_t)i1 * 64 + ln * 4);
      short4_t v2 = *(const short4_t*)(feat + (size_t)i2 * 64 + ln * 4);
      short4_t v3 = *(const short4_t*)(feat + (size_t)i3 * 64 + ln * 4);
#pragma unroll
      for (int d = 0; d < 4; ++d)
        a[d] += (bf2f((unsigned short)v0[d]) + bf2f((unsigned short)v1[d])) +
                (bf2f((unsigned short)v2[d]) + bf2f((unsigned short)v3[d]));
      j += 4;
      if (!more) break;
      i0 = n0; i1 = n1; i2 = n2; i3 = n3;
    }
  }
  if (j + 2 <= deg) {
    int i0 = lidx[j], i1 = lidx[j + 1];
    short4_t v0 = *(const short4_t*)(feat + (size_t)i0 * 64 + ln * 4);
    short4_t v1 = *(const short4_t*)(feat + (size_t)i1 * 64 + ln * 4);
#pragma unroll
    for (int d = 0; d < 4; ++d)
      a[d] += bf2f((unsigned short)v0[d]) + bf2f((unsigned short)v1[d]);
    j += 2;
  }
  if (j < deg) {
    short4_t v = *(const short4_t*)(feat + (size_t)lidx[j] * 64 + ln * 4);
#pragma unroll
    for (int d = 0; d < 4; ++d) a[d] += bf2f((unsigned short)v[d]);
  }
  float sc = deg ? 1.f / (float)deg : 0.f;
  short4_t pk;
#pragma unroll
  for (int d = 0; d < 4; ++d) pk[d] = (short)f2bf(a[d] * sc);
  *(short4_t*)(out + (size_t)node * 64 + ln * 4) = pk;
}

// ---------------------------------------------------------------------------
// Layer-1 GEMM + fused layer-2 edge-transform, both ntypes per dispatch:
//   h   = lrelu(A1@W1[0:128] + A2@W1[128:256] + b1_0 + degmask*b1e)
//   wh2 = h @ W2e            (mean(h)@W = mean(h@W): exact linearity)
// Pass 2 reuses the on-chip h tile: stash h->As (LDS), stage W2e^T->Ws,
// 16 MFMAs/wave, write 64-dim wh2. No extra global reads of h.
// In-place out==A1 safe (own rows; loads hoisted before writes).
// ---------------------------------------------------------------------------
__global__ __launch_bounds__(256) void gemm1_k(
    const unsigned short* __restrict__ A1a, const unsigned short* __restrict__ A2a,
    const unsigned short* __restrict__ WT1a, const float* __restrict__ b0a,
    const float* __restrict__ bea, const int* __restrict__ cura,
    unsigned short* __restrict__ outa, const unsigned short* __restrict__ WT2ea,
    unsigned short* __restrict__ wh2a,
    const unsigned short* __restrict__ A1b, const unsigned short* __restrict__ A2b,
    const unsigned short* __restrict__ WT1b, const float* __restrict__ b0b,
    const float* __restrict__ beb, const int* __restrict__ curb,
    unsigned short* __restrict__ outb, const unsigned short* __restrict__ WT2eb,
    unsigned short* __restrict__ wh2b, int M, int nbA) {
  __shared__ short As[64 * 128];
  __shared__ short Ws[128 * 128];
  __shared__ float degmask[64];

  int blk = blockIdx.x;
  const unsigned short *A1, *A2, *WT1, *WT2e; const float *b0, *be;
  const int* cur; unsigned short *outp, *wh2;
  if (blk < nbA) { A1 = A1a; A2 = A2a; WT1 = WT1a; b0 = b0a; be = bea; cur = cura; outp = outa; WT2e = WT2ea; wh2 = wh2a; }
  else { blk -= nbA; A1 = A1b; A2 = A2b; WT1 = WT1b; b0 = b0b; be = beb; cur = curb; outp = outb; WT2e = WT2eb; wh2 = wh2b; }

  const int tid = threadIdx.x;
  const int lane = tid & 63;
  const int wave = tid >> 6;
  const int row0 = blk * 64;

  short8 aA[4], aB[4];
#pragma unroll
  for (int it = 0; it < 4; ++it) {
    int chunk = tid + it * 256;
    int row = chunk >> 4, c16 = chunk & 15;
    int gr = row0 + row; if (gr > M - 1) gr = M - 1;
    aA[it] = *(const short8*)(A1 + (size_t)gr * 128 + c16 * 8);
    aB[it] = *(const short8*)(A2 + (size_t)gr * 128 + c16 * 8);
  }

  if (tid < 64) {
    int r = row0 + tid;
    degmask[tid] = (r < M && cur[r] > 0) ? 1.f : 0.f;
  }

  f32x4 acc[4][2] = {};

#pragma unroll
  for (int kh = 0; kh < 2; ++kh) {
    __syncthreads();
#pragma unroll
    for (int it = 0; it < 4; ++it) {
      int chunk = tid + it * 256;
      int row = chunk >> 4, c16 = chunk & 15;
      int byteoff = row * 256 + ((c16 * 16) ^ ((row & 7) << 4));
      *(short8*)((char*)As + byteoff) = (kh == 0) ? aA[it] : aB[it];
    }
#pragma unroll
    for (int it = 0; it < 8; ++it) {
      int chunk = tid + it * 256;
      int n = chunk >> 4, c16 = chunk & 15;
      short8 v = *(const short8*)(WT1 + (size_t)n * 256 + kh * 128 + c16 * 8);
      int byteoff = n * 256 + ((c16 * 16) ^ ((n & 7) << 4));
      *(short8*)((char*)Ws + byteoff) = v;
    }
    __syncthreads();

#pragma unroll
    for (int ks = 0; ks < 4; ++ks) {
      short8 af[4];
#pragma unroll
      for (int rf = 0; rf < 4; ++rf) {
        int row = rf * 16 + (lane & 15);
        int c16 = ks * 4 + (lane >> 4);
        int byteoff = row * 256 + ((c16 * 16) ^ ((row & 7) << 4));
        af[rf] = *(const short8*)((const char*)As + byteoff);
      }
      short8 wf[2];
#pragma unroll
      for (int cf = 0; cf < 2; ++cf) {
        int n = wave * 32 + cf * 16 + (lane & 15);
        int c16 = ks * 4 + (lane >> 4);
        int byteoff = n * 256 + ((c16 * 16) ^ ((n & 7) << 4));
        wf[cf] = *(const short8*)((const char*)Ws + byteoff);
      }
#pragma unroll
      for (int rf = 0; rf < 4; ++rf)
#pragma unroll
        for (int cf = 0; cf < 2; ++cf)
          acc[rf][cf] = __builtin_amdgcn_mfma_f32_16x16x32_bf16(
              af[rf], wf[cf], acc[rf][cf], 0, 0, 0);
    }
  }

  __syncthreads();  // all As/Ws reads done before repurposing

  // epilogue: h -> global (in-place) + stash bf16 h into As for pass 2
#pragma unroll
  for (int cf = 0; cf < 2; ++cf) {
    int c = wave * 32 + cf * 16 + (lane & 15);
    float bb0 = b0[c], bbe = be[c];
#pragma unroll
    for (int rf = 0; rf < 4; ++rf) {
#pragma unroll
      for (int j = 0; j < 4; ++j) {
        int lr = rf * 16 + (lane >> 4) * 4 + j;
        int r = row0 + lr;
        float v = acc[rf][cf][j] + bb0 + degmask[lr] * bbe;
        v = (v >= 0.f) ? v : 0.01f * v;
        unsigned short hb = f2bf(v);
        if (r < M) outp[(size_t)r * 128 + c] = hb;
        int byteoff = lr * 256 + (((c >> 3) << 4) ^ ((lr & 7) << 4)) + ((c * 2) & 15);
        *(short*)((char*)As + byteoff) = (short)hb;
      }
    }
  }
  // stage W2e^T (second half of WT2 rows) into Ws: 64 rows x 128 bf16
#pragma unroll
  for (int it = 0; it < 4; ++it) {
    int chunk = tid + it * 256;
    int n = chunk >> 4, c16 = chunk & 15;
    short8 v = *(const short8*)(WT2e + (size_t)n * 256 + 128 + c16 * 8);
    int byteoff = n * 256 + ((c16 * 16) ^ ((n & 7) << 4));
    *(short8*)((char*)Ws + byteoff) = v;
  }
  __syncthreads();

  // pass 2: wh2 = h @ W2e  (N=64: 1 col-frag/wave)
  f32x4 acc2[4] = {};
#pragma unroll
  for (int ks = 0; ks < 4; ++ks) {
    short8 af[4];
#pragma unroll
    for (int rf = 0; rf < 4; ++rf) {
      int row = rf * 16 + (lane & 15);
      int c16 = ks * 4 + (lane >> 4);
      int byteoff = row * 256 + ((c16 * 16) ^ ((row & 7) << 4));
      af[rf] = *(const short8*)((const char*)As + byteoff);
    }
    short8 wf;
    {
      int n = wave * 16 + (lane & 15);
      int c16 = ks * 4 + (lane >> 4);
      int byteoff = n * 256 + ((c16 * 16) ^ ((n & 7) << 4));
      wf = *(const short8*)((const char*)Ws + byteoff);
    }
#pragma unroll
    for (int rf = 0; rf < 4; ++rf)
      acc2[rf] = __builtin_amdgcn_mfma_f32_16x16x32_bf16(af[rf], wf, acc2[rf], 0, 0, 0);
  }
  {
    int c = wave * 16 + (lane & 15);
#pragma unroll
    for (int rf = 0; rf < 4; ++rf)
#pragma unroll
      for (int j = 0; j < 4; ++j) {
        int r = row0 + rf * 16 + (lane >> 4) * 4 + j;
        if (r < M) wh2[(size_t)r * 64 + c] = f2bf(acc2[rf][j]);
      }
  }
}

// ---------------------------------------------------------------------------
// Layer-2 final: out = A1@W2_0 + agg64 + b2_0 + degmask*b2e  (fp32 out).
// K=128 single GEMM; agg64 added in epilogue (64-dim bf16 mean of wh2).
// ---------------------------------------------------------------------------
__global__ __launch_bounds__(256) void gemm2s_k(
    const unsigned short* __restrict__ A1a, const unsigned short* __restrict__ agga,
    const unsigned short* __restrict__ WTa, const float* __restrict__ b0a,
    const float* __restrict__ bea, const int* __restrict__ cura,
    float* __restrict__ outa,
    const unsigned short* __restrict__ A1b, const unsigned short* __restrict__ aggb,
    const unsigned short* __restrict__ WTb, const float* __restrict__ b0b,
    const float* __restrict__ beb, const int* __restrict__ curb,
    float* __restrict__ outb, int M, int nbA) {
  __shared__ short As[64 * 128];
  __shared__ short Ws[64 * 128];
  __shared__ float degmask[64];

  int blk = blockIdx.x;
  const unsigned short *A1, *agg, *WT; const float *b0, *be; const int* cur;
  float* outp;
  if (blk < nbA) { A1 = A1a; agg = agga; WT = WTa; b0 = b0a; be = bea; cur = cura; outp = outa; }
  else { blk -= nbA; A1 = A1b; agg = aggb; WT = WTb; b0 = b0b; be = beb; cur = curb; outp = outb; }

  const int tid = threadIdx.x;
  const int lane = tid & 63;
  const int wave = tid >> 6;
  const int row0 = blk * 64;

  short8 aA[4];
#pragma unroll
  for (int it = 0; it < 4; ++it) {
    int chunk = tid + it * 256;
    int row = chunk >> 4, c16 = chunk & 15;
    int gr = row0 + row; if (gr > M - 1) gr = M - 1;
    aA[it] = *(const short8*)(A1 + (size_t)gr * 128 + c16 * 8);
  }
  if (tid < 64) {
    int r = row0 + tid;
    degmask[tid] = (r < M && cur[r] > 0) ? 1.f : 0.f;
  }
#pragma unroll
  for (int it = 0; it < 4; ++it) {
    int chunk = tid + it * 256;
    int row = chunk >> 4, c16 = chunk & 15;
    int byteoff = row * 256 + ((c16 * 16) ^ ((row & 7) << 4));
    *(short8*)((char*)As + byteoff) = aA[it];
  }
#pragma unroll
  for (int it = 0; it < 4; ++it) {
    int chunk = tid + it * 256;
    int n = chunk >> 4, c16 = chunk & 15;
    short8 v = *(const short8*)(WT + (size_t)n * 256 + c16 * 8);  // first half = W2_0^T
    int byteoff = n * 256 + ((c16 * 16) ^ ((n & 7) << 4));
    *(short8*)((char*)Ws + byteoff) = v;
  }
  __syncthreads();

  f32x4 acc[4] = {};
#pragma unroll
  for (int ks = 0; ks < 4; ++ks) {
    short8 af[4];
#pragma unroll
    for (int rf = 0; rf < 4; ++rf) {
      int row = rf * 16 + (lane & 15);
      int c16 = ks * 4 + (lane >> 4);
      int byteoff = row * 256 + ((c16 * 16) ^ ((row & 7) << 4));
      af[rf] = *(const short8*)((const char*)As + byteoff);
    }
    short8 wf;
    {
      int n = wave * 16 + (lane & 15);
      int c16 = ks * 4 + (lane >> 4);
      int byteoff = n * 256 + ((c16 * 16) ^ ((n & 7) << 4));
      wf = *(const short8*)((const char*)Ws + byteoff);
    }
#pragma unroll
    for (int rf = 0; rf < 4; ++rf)
      acc[rf] = __builtin_amdgcn_mfma_f32_16x16x32_bf16(af[rf], wf, acc[rf], 0, 0, 0);
  }

  {
    int c = wave * 16 + (lane & 15);
    float bb0 = b0[c], bbe = be[c];
#pragma unroll
    for (int rf = 0; rf < 4; ++rf)
#pragma unroll
      for (int j = 0; j < 4; ++j) {
        int lr = rf * 16 + (lane >> 4) * 4 + j;
        int r = row0 + lr;
        if (r < M) {
          float v = acc[rf][j] + bf2f(agg[(size_t)r * 64 + c]) + bb0 +
                    degmask[lr] * bbe;
          outp[(size_t)r * 64 + c] = v;
        }
      }
  }
}

extern "C" void kernel_launch(void* const* d_in, const int* in_sizes, int n_in,
                              void* d_out, int out_size, void* d_ws,
                              size_t ws_size, hipStream_t stream) {
  const float* emb_u = (const float*)d_in[0];
  const float* emb_i = (const float*)d_in[1];
  const float* W1_0  = (const float*)d_in[2];
  const float* b1_0  = (const float*)d_in[3];
  const float* W1_ui = (const float*)d_in[4];
  const float* b1_ui = (const float*)d_in[5];
  const float* W1_iu = (const float*)d_in[6];
  const float* b1_iu = (const float*)d_in[7];
  const float* W2_0  = (const float*)d_in[8];
  const float* b2_0  = (const float*)d_in[9];
  const float* W2_ui = (const float*)d_in[10];
  const float* b2_ui = (const float*)d_in[11];
  const float* W2_iu = (const float*)d_in[12];
  const float* b2_iu = (const float*)d_in[13];
  const int* src_ui = (const int*)d_in[14];
  const int* dst_ui = (const int*)d_in[15];
  const int* src_iu = (const int*)d_in[16];
  const int* dst_iu = (const int*)d_in[17];
  float* out = (float*)d_out;

  // ---- workspace layout (~129 MB) ----
  char* p = (char*)d_ws;
  unsigned short* WT1i = (unsigned short*)p; p += 65536;
  unsigned short* WT1u = (unsigned short*)p; p += 65536;
  unsigned short* WT2i = (unsigned short*)p; p += 32768;
  unsigned short* WT2u = (unsigned short*)p; p += 32768;
  int* cur_i = (int*)p; p += 400128;
  int* cur_u = (int*)p; p += 400128;
  int* csr_ui = (int*)p; p += (size_t)100032 * DEGCAP * 4;  // 12.8 MB
  int* csr_iu = (int*)p; p += (size_t)100032 * DEGCAP * 4;
  const size_t FB = (size_t)N_USER * 128 * 2;        // 25.6 MB
  unsigned short* ebu  = (unsigned short*)p; p += FB;  // -> hu (in place)
  unsigned short* ebi  = (unsigned short*)p; p += FB;  // -> hi (in place)
  const size_t HB = (size_t)100032 * 64 * 2;         // 12.8 MB
  unsigned short* wh2u = (unsigned short*)p; p += HB;
  unsigned short* wh2i = (unsigned short*)p; p += HB;
  unsigned short* ag64A = (unsigned short*)p; p += HB;  // item-side mean
  unsigned short* ag64B = (unsigned short*)p; p += HB;  // user-side mean
  unsigned short* hu = ebu;
  unsigned short* hi = ebi;
  // layer-1 agg buffers alias d_out (dead until gemm2s writes out; gemm1
  // reads them and writes h to eb, so no conflict):
  unsigned short* aggB = (unsigned short*)out;                          // user
  unsigned short* aggA = (unsigned short*)(out + (size_t)N_USER * 64);  // item

  const int GG = (N_USER + 63) / 64;  // 1563

  hipMemsetAsync(cur_i, 0, 2 * 400128, stream);
  setup_k<<<B_TOT, 256, 0, stream>>>(src_ui, dst_ui, cur_i, csr_ui,
                                     src_iu, dst_iu, cur_u, csr_iu,
                                     emb_u, emb_i, ebu, ebi,
                                     W1_0, W1_ui, W1_iu, W2_0, W2_ui, W2_iu,
                                     WT1i, WT1u, WT2i, WT2u);

  // ---- layer 1: gather-mean, fused GEMM + lrelu + layer-2 edge-transform --
  aggc_k<<<2 * 6250, 256, 0, stream>>>(
      ebu, cur_i, csr_ui, aggA, ebi, cur_u, csr_iu, aggB, 6250);
  gemm1_k<<<2 * GG, 256, 0, stream>>>(
      ebi, aggA, WT1i, b1_0, b1_ui, cur_i, hi, WT2u, wh2i,   // h_i; wh2i=h_i@W2iu
      ebu, aggB, WT1u, b1_0, b1_iu, cur_u, hu, WT2i, wh2u,   // h_u; wh2u=h_u@W2ui
      N_USER, GG);

  // ---- layer 2: 64-dim gather-mean of wh2, final K=128 GEMM -> fp32 out ---
  agg64_k<<<2 * 6250, 256, 0, stream>>>(
      wh2u, cur_i, csr_ui, ag64A, wh2i, cur_u, csr_iu, ag64B, 6250);
  gemm2s_k<<<2 * GG, 256, 0, stream>>>(
      hi, ag64A, WT2i, b2_0, b2_ui, cur_i, out + (size_t)N_USER * 64,
      hu, ag64B, WT2u, b2_0, b2_iu, cur_u, out, N_USER, GG);
}